// Round 14
// baseline (431.759 us; speedup 1.0000x reference)
//
#include <hip/hip_runtime.h>
#include <hip/hip_bf16.h>
#include <stdint.h>

#define TT 512
#define NB 128
#define EM 256
#define UN 256
#define XS 68   // xstage row stride in bytes (64 steps + 4 pad -> conflict-free)

typedef float floatx4 __attribute__((ext_vector_type(4)));
typedef int v8i __attribute__((ext_vector_type(8)));

#define SCALE_Q 0x7B7B7B7BU   // e8m0 123 = 2^-4 (operands stored x16)
#define SCALE_A 0x7D7D7D7DU   // e8m0 125 = 2^-2 (h stored as 4*h)

// barrier without vmcnt drain: LDS-ordered only (gather loads stay in flight)
#define BAR() asm volatile("s_waitcnt lgkmcnt(0)\n\ts_barrier" ::: "memory")

__device__ inline unsigned char f2fp8(float f) {
    int pk = __builtin_amdgcn_cvt_pk_fp8_f32(f, f, 0, false);  // OCP e4m3
    return (unsigned char)(pk & 0xff);
}
__device__ inline float fp8dec(uint32_t word, int sel) {
    return __builtin_amdgcn_cvt_f32_fp8(word >> (8 * sel), 0);
}

// ---------------------------------------------------------------------------
// Kernel 1: blocks 0..31: W*16 -> fp8 B-frags (K=128 layout).
//           blocks 32..63: U*16 -> fp8 B-frags (same layout).
// frag[((kh*16+nt)*64+lane)*32+j] = fp8(16*M[nt*16+(lane&15)][kh*128+(lane>>4)*32+j])
// ---------------------------------------------------------------------------
__global__ void k_pack(const float* __restrict__ W, const float* __restrict__ U,
                       unsigned char* __restrict__ wfrag8, unsigned char* __restrict__ ufrag8) {
    int bid = blockIdx.x;
    const float* src = (bid < 32) ? W : U;
    unsigned char* dstbase = (bid < 32) ? wfrag8 : ufrag8;
    int idx = (bid & 31) * 256 + threadIdx.x;  // 0..8191
    int jg   = idx & 3;
    int lane = (idx >> 2) & 63;
    int tile = idx >> 8;            // kh*16 + nt
    int nt = tile & 15, kh = tile >> 4;
    int u  = nt * 16 + (lane & 15);
    int k0 = kh * 128 + (lane >> 4) * 32 + jg * 8;
    unsigned char* dst = dstbase + ((size_t)tile * 64 + lane) * 32 + jg * 8;
    #pragma unroll
    for (int j = 0; j < 8; j++) dst[j] = f2fp8(16.f * src[u * EM + k0 + j]);
}

// ---------------------------------------------------------------------------
// Kernel 2 (v13): fully fused. 128 blocks x 256 thr.
// Scan core = R13-exact (8 scaled MFMA, 4 tiles x 2-chain, poly tanh,
// lgkm-only BAR). xw never touches global memory: wave w computes next
// chunk's xw for ITS OWN units (64w..64w+63) into double-buffered LDS
// xstage[2][unit][68] -- wave-local produce/consume, no extra sync.
// Per 16-step phase (mt=ls>>4): ph0 token load, ph2 16 float4 emb gather,
// ph8 quantize + 8 scaled MFMA (4 N-tiles x 2 kh) + 4 packed b32 writes.
// ---------------------------------------------------------------------------
__global__ __launch_bounds__(256, 1) void k_rnn(
    const int* __restrict__ sent, const float* __restrict__ emb,
    const unsigned char* __restrict__ wfrag8, const unsigned char* __restrict__ ufrag8,
    const float* __restrict__ W1, const float* __restrict__ b1,
    const float* __restrict__ W2, const float* __restrict__ b2,
    float* __restrict__ out)
{
    __shared__ __align__(16) unsigned char hb8[2][256];
    __shared__ __align__(16) unsigned char xs[2][256 * XS];   // 2 x 17 KB
    __shared__ float hid[32];
    const int t    = threadIdx.x;
    const int lane = t & 63;
    const int w    = t >> 6;
    const int kg   = lane >> 4;
    const int m15  = lane & 15;
    const int b    = blockIdx.x;

    // U and W fp8 B-frags -> registers: tiles nt = 4w+q (this wave's units)
    v8i ufr8[4][2], wfr8[4][2];
    #pragma unroll
    for (int q = 0; q < 4; q++) {
        #pragma unroll
        for (int kh = 0; kh < 2; kh++) {
            size_t off = ((size_t)(kh * 16 + 4 * w + q) * 64 + lane) * 32;
            union { uint4 u4[2]; v8i v; } cu, cw;
            cu.u4[0] = *(const uint4*)(ufrag8 + off);
            cu.u4[1] = *(const uint4*)(ufrag8 + off + 16);
            cw.u4[0] = *(const uint4*)(wfrag8 + off);
            cw.u4[1] = *(const uint4*)(wfrag8 + off + 16);
            ufr8[q][kh] = cu.v;
            wfr8[q][kh] = cw.v;
        }
    }

    const int* sb = sent + b * TT;
    const int ubase = 64 * w + m15;          // unit of this lane's D column
    const int xrow  = t * XS;                // xf read base (unit = t)
    const floatx4 zero4 = {0.f, 0.f, 0.f, 0.f};

    // ---- prologue: compute chunk 0 (steps 0..63) into xs[0]
    #pragma unroll
    for (int mt = 0; mt < 4; mt++) {
        int tok = sb[mt * 16 + m15];
        const float* ar = emb + (size_t)tok * EM;
        union { uint32_t d[8]; v8i v; } A[2];
        #pragma unroll
        for (int kh = 0; kh < 2; kh++) {
            const float* p = ar + kh * 128 + kg * 32;
            #pragma unroll
            for (int d = 0; d < 8; d++) {
                float4 f = *(const float4*)(p + 4 * d);
                int pk = __builtin_amdgcn_cvt_pk_fp8_f32(16.f * f.x, 16.f * f.y, 0, false);
                pk     = __builtin_amdgcn_cvt_pk_fp8_f32(16.f * f.z, 16.f * f.w, pk, true);
                A[kh].d[d] = (uint32_t)pk;
            }
        }
        #pragma unroll
        for (int q = 0; q < 4; q++) {
            floatx4 acc = __builtin_amdgcn_mfma_scale_f32_16x16x128_f8f6f4(
                              A[0].v, wfr8[q][0], zero4, 0, 0, 0, SCALE_Q, 0, SCALE_Q);
            acc = __builtin_amdgcn_mfma_scale_f32_16x16x128_f8f6f4(
                              A[1].v, wfr8[q][1], acc, 0, 0, 0, SCALE_Q, 0, SCALE_Q);
            int pk = __builtin_amdgcn_cvt_pk_fp8_f32(16.f * acc[0], 16.f * acc[1], 0, false);
            pk     = __builtin_amdgcn_cvt_pk_fp8_f32(16.f * acc[2], 16.f * acc[3], pk, true);
            *(uint32_t*)&xs[0][(ubase + q * 16) * XS + mt * 16 + kg * 4] = (uint32_t)pk;
        }
    }

    hb8[0][t] = 0; hb8[1][t] = 0;
    __syncthreads();

    int cur = 0;
    const float c3 = -0.33333334f, c5 = 0.13333334f, c7 = -0.05396825f, c9 = 0.02186949f;
    const int sel = kg;

    float4 fa[16];   // gather staging for next chunk (one mt at a time)
    int tokr = 0;

    for (int s = 0; s < TT; s++) {
        const int ls   = s & 63;
        const int xbuf = (s >> 6) & 1;
        float xf = fp8dec((uint32_t)xs[xbuf][xrow + ls], 0) * 0.0625f;   // /16

        // ---- scan core (R13-exact) ----
        const unsigned char* hc = hb8[cur];
        union { uint4 u4[2]; v8i v; } A0, A1;
        A0.u4[0] = *(const uint4*)(hc + kg * 32);
        A0.u4[1] = *(const uint4*)(hc + kg * 32 + 16);
        A1.u4[0] = *(const uint4*)(hc + 128 + kg * 32);
        A1.u4[1] = *(const uint4*)(hc + 128 + kg * 32 + 16);

        float z[4];
        #pragma unroll
        for (int q = 0; q < 4; q++) {
            floatx4 acc = __builtin_amdgcn_mfma_scale_f32_16x16x128_f8f6f4(
                              A0.v, ufr8[q][0], zero4, 0, 0, 0, SCALE_A, 0, SCALE_Q);
            acc = __builtin_amdgcn_mfma_scale_f32_16x16x128_f8f6f4(
                              A1.v, ufr8[q][1], acc, 0, 0, 0, SCALE_A, 0, SCALE_Q);
            z[q] = acc[0];
        }

        float zz = (sel == 0) ? z[0] : (sel == 1) ? z[1] : (sel == 2) ? z[2] : z[3];
        zz += xf;

        float hn;
        if (__builtin_expect(fabsf(zz) > 0.75f, 0)) {
            float e = __expf(2.f * zz);
            hn = 1.f - 2.f * __builtin_amdgcn_rcpf(e + 1.f);
        } else {
            float x2f = zz * zz;
            float p = fmaf(x2f, c9, c7);
            p = fmaf(x2f, p, c5);
            p = fmaf(x2f, p, c3);
            hn = fmaf(zz * x2f, p, zz);
        }

        hb8[cur ^ 1][t] = f2fp8(4.f * hn);

        // ---- pipelined gemm for next chunk (chunks 0..6 build 1..7) ----
        if (s < TT - 64) {
            const int ph = ls & 15;
            const int mt = ls >> 4;
            const int base = (s & ~63) + 64;
            if (ph == 0) {
                tokr = sb[base + mt * 16 + m15];
            } else if (ph == 2) {
                const float* ar = emb + (size_t)tokr * EM;
                #pragma unroll
                for (int kh = 0; kh < 2; kh++) {
                    const float* p = ar + kh * 128 + kg * 32;
                    #pragma unroll
                    for (int d = 0; d < 8; d++) fa[kh * 8 + d] = *(const float4*)(p + 4 * d);
                }
            } else if (ph == 8) {
                union { uint32_t d[8]; v8i v; } A[2];
                #pragma unroll
                for (int kh = 0; kh < 2; kh++) {
                    #pragma unroll
                    for (int d = 0; d < 8; d++) {
                        float4 f = fa[kh * 8 + d];
                        int pk = __builtin_amdgcn_cvt_pk_fp8_f32(16.f * f.x, 16.f * f.y, 0, false);
                        pk     = __builtin_amdgcn_cvt_pk_fp8_f32(16.f * f.z, 16.f * f.w, pk, true);
                        A[kh].d[d] = (uint32_t)pk;
                    }
                }
                const int nxt = xbuf ^ 1;
                #pragma unroll
                for (int q = 0; q < 4; q++) {
                    floatx4 acc = __builtin_amdgcn_mfma_scale_f32_16x16x128_f8f6f4(
                                      A[0].v, wfr8[q][0], zero4, 0, 0, 0, SCALE_Q, 0, SCALE_Q);
                    acc = __builtin_amdgcn_mfma_scale_f32_16x16x128_f8f6f4(
                                      A[1].v, wfr8[q][1], acc, 0, 0, 0, SCALE_Q, 0, SCALE_Q);
                    int pk = __builtin_amdgcn_cvt_pk_fp8_f32(16.f * acc[0], 16.f * acc[1], 0, false);
                    pk     = __builtin_amdgcn_cvt_pk_fp8_f32(16.f * acc[2], 16.f * acc[3], pk, true);
                    *(uint32_t*)&xs[nxt][(ubase + q * 16) * XS + mt * 16 + kg * 4] = (uint32_t)pk;
                }
            }
        }

        BAR();
        cur ^= 1;
    }

    // ---- head: hidden = relu(h @ W1 + b1); logits; softmax (h = fp8/4)
    if (t < 32) {
        float a = b1[t];
        for (int k = 0; k < 256; k++) {
            uint32_t wd = *(const uint32_t*)&hb8[cur][k & ~3];
            a += 0.25f * fp8dec(wd, k & 3) * W1[k * 32 + t];
        }
        hid[t] = fmaxf(a, 0.f);
    }
    __syncthreads();
    if (t == 0) {
        float l0 = b2[0], l1 = b2[1];
        #pragma unroll
        for (int i = 0; i < 32; i++) {
            float hv = hid[i];
            l0 += hv * W2[2 * i];
            l1 += hv * W2[2 * i + 1];
        }
        float mx2 = fmaxf(l0, l1);
        float e0 = __expf(l0 - mx2), e1 = __expf(l1 - mx2);
        float inv = 1.f / (e0 + e1);
        out[2 * b]     = e0 * inv;
        out[2 * b + 1] = e1 * inv;
    }
}

extern "C" void kernel_launch(void* const* d_in, const int* in_sizes, int n_in,
                              void* d_out, int out_size, void* d_ws, size_t ws_size,
                              hipStream_t stream) {
    const int*   sent = (const int*)d_in[0];
    const float* emb  = (const float*)d_in[1];
    const float* W    = (const float*)d_in[2];
    const float* U    = (const float*)d_in[3];
    const float* W1   = (const float*)d_in[4];
    const float* b1   = (const float*)d_in[5];
    const float* W2   = (const float*)d_in[6];
    const float* b2   = (const float*)d_in[7];
    float* out = (float*)d_out;

    unsigned char* wfrag8 = (unsigned char*)d_ws;            // 64 KB
    unsigned char* ufrag8 = wfrag8 + (size_t)UN * EM;        // 64 KB

    k_pack<<<64, 256, 0, stream>>>(W, U, wfrag8, ufrag8);
    k_rnn<<<NB, 256, 0, stream>>>(sent, emb, wfrag8, ufrag8, W1, b1, W2, b2, out);
}